// Round 5
// baseline (1580.908 us; speedup 1.0000x reference)
//
#include <hip/hip_runtime.h>
#include <stdint.h>

#define D 256
#define RREL 16
#define BB 8
#define K9 2304          // (BB+1)*D
#define KIT (K9 / 64)    // 36 k-iterations
#define LN_EPS 1e-5f

typedef __attribute__((ext_vector_type(8))) short frag8;
typedef __attribute__((ext_vector_type(4))) float floatx4;

__device__ __forceinline__ unsigned short f2bf(float f) {
    union { float f; uint32_t u; } v; v.f = f;
    uint32_t r = (v.u + 0x7FFFu + ((v.u >> 16) & 1u)) >> 16;
    return (unsigned short)r;
}
__device__ __forceinline__ float bf2f(unsigned short u) {
    union { uint32_t u; float f; } v; v.u = (uint32_t)u << 16;
    return v.f;
}

// ---------- fused: fp32->bf16 convert + degree histogram ----------
__global__ __launch_bounds__(256) void k_pre(const float* __restrict__ x,
                                             unsigned short* __restrict__ xb, int n4,
                                             const int* __restrict__ ei,
                                             int* __restrict__ deg, int E) {
    int i = blockIdx.x * 256 + threadIdx.x;
    if (i < n4) {
        float4 v = ((const float4*)x)[i];
        ((ushort4*)xb)[i] = make_ushort4(f2bf(v.x), f2bf(v.y), f2bf(v.z), f2bf(v.w));
    }
    if (i < E) atomicAdd(&deg[ei[E + i]], 1);
}

// ---------- CSR scans ----------
__global__ __launch_bounds__(256) void k_scan1(const int* __restrict__ deg,
                                               int* __restrict__ csum, int N) {
    __shared__ int sh[256];
    int n = blockIdx.x * 256 + threadIdx.x;
    sh[threadIdx.x] = (n < N) ? deg[n] : 0;
    __syncthreads();
    for (int off = 128; off > 0; off >>= 1) {
        if (threadIdx.x < off) sh[threadIdx.x] += sh[threadIdx.x + off];
        __syncthreads();
    }
    if (threadIdx.x == 0) csum[blockIdx.x] = sh[0];
}

// parallel exclusive scan of chunk sums (nch <= 256 fast path)
__global__ __launch_bounds__(256) void k_scan2(int* __restrict__ csum, int nch,
                                               int* __restrict__ rowptr, int N) {
    int tid = threadIdx.x;
    if (nch <= 256) {
        __shared__ int sh[256];
        int v = (tid < nch) ? csum[tid] : 0;
        sh[tid] = v;
        __syncthreads();
        for (int off = 1; off < 256; off <<= 1) {
            int t = (tid >= off) ? sh[tid - off] : 0;
            __syncthreads();
            sh[tid] += t;
            __syncthreads();
        }
        if (tid < nch) csum[tid] = sh[tid] - v;
        if (tid == 255) rowptr[N] = sh[255];
    } else if (tid == 0) {
        int s = 0;
        for (int i = 0; i < nch; ++i) { int c = csum[i]; csum[i] = s; s += c; }
        rowptr[N] = s;
    }
}

__global__ __launch_bounds__(256) void k_scan3(const int* __restrict__ deg,
                                               const int* __restrict__ csum,
                                               int* __restrict__ rowptr,
                                               int* __restrict__ cursor,
                                               float* __restrict__ cnt, int N) {
    __shared__ int sh[256];
    int tid = threadIdx.x;
    int n = blockIdx.x * 256 + tid;
    int v = (n < N) ? deg[n] : 0;
    sh[tid] = v;
    __syncthreads();
    for (int off = 1; off < 256; off <<= 1) {
        int t = (tid >= off) ? sh[tid - off] : 0;
        __syncthreads();
        sh[tid] += t;
        __syncthreads();
    }
    int excl = sh[tid] - v + csum[blockIdx.x];
    if (n < N) {
        rowptr[n] = excl;
        cursor[n] = excl;
        cnt[n] = (float)(v + 1);
    }
}

__global__ void k_scatter(const int* __restrict__ ei, const int* __restrict__ et,
                          const float* __restrict__ ea, int* __restrict__ cursor,
                          int2* __restrict__ ep, int E) {
    int e = blockIdx.x * 256 + threadIdx.x;
    if (e >= E) return;
    int dst = ei[E + e];
    int p = atomicAdd(&cursor[dst], 1);
    ep[p] = make_int2(ei[e] | (et[e] << 24), __float_as_int(ea[e]));
}

// ---------- weight prep, both layers in one dispatch ----------
__global__ __launch_bounds__(256) void k_prep_w(const float* __restrict__ basis1,
                                                const float* __restrict__ root1,
                                                unsigned short* __restrict__ Wt1,
                                                const float* __restrict__ basis2,
                                                const float* __restrict__ root2,
                                                unsigned short* __restrict__ Wt2) {
    __shared__ float tile[64][65];
    const float* basis = blockIdx.z ? basis2 : basis1;
    const float* root  = blockIdx.z ? root2 : root1;
    unsigned short* Wt = blockIdx.z ? Wt2 : Wt1;
    int k0 = blockIdx.x * 64, o0 = blockIdx.y * 64;
    const float* src = (k0 < BB * D) ? (basis + (size_t)k0 * D)
                                     : (root + (size_t)(k0 - BB * D) * D);
    int tid = threadIdx.x;
#pragma unroll
    for (int t = 0; t < 16; ++t) {
        int idx = t * 256 + tid;
        int kk = idx >> 6, oo = idx & 63;
        tile[kk][oo] = src[(size_t)kk * D + o0 + oo];
    }
    __syncthreads();
#pragma unroll
    for (int t = 0; t < 16; ++t) {
        int idx = t * 256 + tid;
        int oo = idx >> 6, kk = idx & 63;
        Wt[(size_t)(o0 + oo) * K9 + k0 + kk] = f2bf(tile[kk][oo]);
    }
}

// ---------- gather: one wave per node, bf16 in/out, 4-deep edge unroll ----------
__global__ __launch_bounds__(256) void k_gather(
    const unsigned short* __restrict__ xb, const float* __restrict__ att,
    const int* __restrict__ rowptr, const int2* __restrict__ ep,
    const float* __restrict__ cnt, unsigned short* __restrict__ G,
    int n0, int rows, int N) {
    __shared__ float att_s[RREL * BB];
    int tid = threadIdx.x;
    if (tid < RREL * BB) att_s[tid] = att[tid];
    __syncthreads();
    int wv = tid >> 6, lane = tid & 63;
    int rloc = blockIdx.x * 4 + wv;
    if (rloc >= rows) return;
    int n = n0 + rloc;
    unsigned short* gout = G + (size_t)rloc * K9 + lane * 4;
    if (n >= N) {
        ushort4 z = make_ushort4(0, 0, 0, 0);
#pragma unroll
        for (int b = 0; b <= BB; ++b) *(ushort4*)(gout + b * D) = z;
        return;
    }
    ushort4 xu = *(const ushort4*)&xb[(size_t)n * D + lane * 4];
    float xv[4] = {bf2f(xu.x), bf2f(xu.y), bf2f(xu.z), bf2f(xu.w)};
    float g[BB][4];
#pragma unroll
    for (int b = 0; b < BB; ++b) {
        float a = att_s[(RREL - 1) * BB + b];
#pragma unroll
        for (int j = 0; j < 4; ++j) g[b][j] = a * xv[j];
    }
    int e0 = rowptr[n], e1 = rowptr[n + 1];
    int e = e0;
    for (; e + 4 <= e1; e += 4) {           // 4 outstanding row loads
        int2 p0 = ep[e], p1 = ep[e + 1], p2 = ep[e + 2], p3 = ep[e + 3];
        ushort4 u0 = *(const ushort4*)&xb[(size_t)(p0.x & 0xFFFFFF) * D + lane * 4];
        ushort4 u1 = *(const ushort4*)&xb[(size_t)(p1.x & 0xFFFFFF) * D + lane * 4];
        ushort4 u2 = *(const ushort4*)&xb[(size_t)(p2.x & 0xFFFFFF) * D + lane * 4];
        ushort4 u3 = *(const ushort4*)&xb[(size_t)(p3.x & 0xFFFFFF) * D + lane * 4];
        float w0 = __int_as_float(p0.y), w1 = __int_as_float(p1.y);
        float w2 = __int_as_float(p2.y), w3 = __int_as_float(p3.y);
        int r0 = (unsigned)p0.x >> 24, r1 = (unsigned)p1.x >> 24;
        int r2 = (unsigned)p2.x >> 24, r3 = (unsigned)p3.x >> 24;
        float a0[4] = {bf2f(u0.x), bf2f(u0.y), bf2f(u0.z), bf2f(u0.w)};
        float a1[4] = {bf2f(u1.x), bf2f(u1.y), bf2f(u1.z), bf2f(u1.w)};
        float a2[4] = {bf2f(u2.x), bf2f(u2.y), bf2f(u2.z), bf2f(u2.w)};
        float a3[4] = {bf2f(u3.x), bf2f(u3.y), bf2f(u3.z), bf2f(u3.w)};
#pragma unroll
        for (int b = 0; b < BB; ++b) {
            float c0 = w0 * att_s[r0 * BB + b];
            float c1 = w1 * att_s[r1 * BB + b];
            float c2 = w2 * att_s[r2 * BB + b];
            float c3 = w3 * att_s[r3 * BB + b];
#pragma unroll
            for (int j = 0; j < 4; ++j)
                g[b][j] += c0 * a0[j] + c1 * a1[j] + c2 * a2[j] + c3 * a3[j];
        }
    }
    for (; e < e1; ++e) {
        int2 pa = ep[e];
        ushort4 ua = *(const ushort4*)&xb[(size_t)(pa.x & 0xFFFFFF) * D + lane * 4];
        float wa = __int_as_float(pa.y);
        int ra = (unsigned)pa.x >> 24;
        float xa[4] = {bf2f(ua.x), bf2f(ua.y), bf2f(ua.z), bf2f(ua.w)};
#pragma unroll
        for (int b = 0; b < BB; ++b) {
            float ca = wa * att_s[ra * BB + b];
#pragma unroll
            for (int j = 0; j < 4; ++j) g[b][j] += ca * xa[j];
        }
    }
#pragma unroll
    for (int b = 0; b < BB; ++b) {
        ushort4 o = make_ushort4(f2bf(g[b][0]), f2bf(g[b][1]), f2bf(g[b][2]), f2bf(g[b][3]));
        *(ushort4*)(gout + b * D) = o;
    }
    float cn = cnt[n];
    ushort4 o = make_ushort4(f2bf(cn * xv[0]), f2bf(cn * xv[1]),
                             f2bf(cn * xv[2]), f2bf(cn * xv[3]));
    *(ushort4*)(gout + BB * D) = o;
}

// ---------- fused GEMM (64x256, K=2304, bf16 MFMA) + mean + residual + LN + ReLU ----------
// Register-staged pipeline: glob->VGPR(40)->ds_write; tile it+1's loads issue before
// tile it's MFMA phase, so L2 latency hides behind compute (no vmcnt drain at barrier).
// LDS = 40960 B -> 4 blocks/CU cap (grid gives ~3).
__global__ __launch_bounds__(256, 4) void k_gemm(
    const unsigned short* __restrict__ G, const unsigned short* __restrict__ Wt,
    const float* __restrict__ hin, const float* __restrict__ cnt,
    const float* __restrict__ bias, const float* __restrict__ gln,
    const float* __restrict__ bln, float* __restrict__ hout,
    unsigned short* __restrict__ houtb, int n0, int N) {
    __shared__ __align__(16) char smem[40960];
    char* Asb = smem;
    char* Bsb = smem + 8192;
    float* ps   = (float*)smem;          // epilogue aliases (A-staging idle then)
    float* pq   = ps + 256;
    float* mu_s = ps + 512;
    float* rs_s = ps + 576;

    int tid = threadIdx.x;
    int wv = tid >> 6, lane = tid & 63;
    int quad = lane >> 4, l16 = lane & 15;
    int grow = blockIdx.x * 64;
    int nb = n0 + grow;

    // 10 granules per thread: gi = t*256 + tid; gi<512 -> A, else B.
    const unsigned short* gsrc[10];
    char* ldst[10];
#pragma unroll
    for (int t = 0; t < 10; ++t) {
        int gi = t * 256 + tid;
        if (gi < 512) {
            int arow = gi >> 3, aslot = gi & 7;
            gsrc[t] = G + (size_t)(grow + arow) * K9 + aslot * 8;
            ldst[t] = Asb + arow * 128 + ((aslot ^ (arow & 7)) << 4);
        } else {
            int bi = gi - 512;
            int brow = bi >> 3, bslot = bi & 7;
            gsrc[t] = Wt + (size_t)brow * K9 + bslot * 8;
            ldst[t] = Bsb + brow * 128 + ((bslot ^ (brow & 7)) << 4);
        }
    }

    floatx4 acc[4][4];
#pragma unroll
    for (int mf = 0; mf < 4; ++mf)
#pragma unroll
        for (int nf = 0; nf < 4; ++nf) acc[mf][nf] = (floatx4){0.f, 0.f, 0.f, 0.f};

    uint4 r[10];
#pragma unroll
    for (int t = 0; t < 10; ++t) r[t] = *(const uint4*)(gsrc[t]);   // tile 0

    for (int it = 0; it < KIT; ++it) {
        if (it) __syncthreads();          // prior iter's ds_reads complete
#pragma unroll
        for (int t = 0; t < 10; ++t) *(uint4*)ldst[t] = r[t];       // waits vmcnt via dep
        __syncthreads();
        if (it + 1 < KIT) {
            int koff = (it + 1) * 64;
#pragma unroll
            for (int t = 0; t < 10; ++t) r[t] = *(const uint4*)(gsrc[t] + koff);
        }
#pragma unroll
        for (int kc = 0; kc < 2; ++kc) {
            int g = kc * 4 + quad;
            frag8 a[4], b[4];
#pragma unroll
            for (int mf = 0; mf < 4; ++mf) {
                int arow = mf * 16 + l16;
                a[mf] = *(const frag8*)(Asb + arow * 128 + ((g ^ (arow & 7)) << 4));
            }
#pragma unroll
            for (int nf = 0; nf < 4; ++nf) {
                int brow = wv * 64 + nf * 16 + l16;
                b[nf] = *(const frag8*)(Bsb + brow * 128 + ((g ^ (brow & 7)) << 4));
            }
#pragma unroll
            for (int mf = 0; mf < 4; ++mf)
#pragma unroll
                for (int nf = 0; nf < 4; ++nf)
                    acc[mf][nf] = __builtin_amdgcn_mfma_f32_16x16x32_bf16(
                        a[mf], b[nf], acc[mf][nf], 0, 0, 0);
        }
    }
    __syncthreads();

    // ---- pass 1: val = acc/cnt + residual + bias; LN partials ----
    int col[4]; float bic[4];
#pragma unroll
    for (int nf = 0; nf < 4; ++nf) {
        col[nf] = wv * 64 + nf * 16 + l16;
        bic[nf] = bias[col[nf]];
    }
#pragma unroll
    for (int mf = 0; mf < 4; ++mf) {
#pragma unroll
        for (int rr = 0; rr < 4; ++rr) {
            int row = mf * 16 + quad * 4 + rr;
            int n = nb + row;
            float s = 0.f, sq = 0.f;
            if (n < N) {
                float inv = 1.0f / cnt[n];
                const float* hp = hin + (size_t)n * D;
#pragma unroll
                for (int nf = 0; nf < 4; ++nf) {
                    float v = acc[mf][nf][rr] * inv + hp[col[nf]] + bic[nf];
                    acc[mf][nf][rr] = v;
                    s += v; sq += v * v;
                }
            }
            s += __shfl_xor(s, 1); sq += __shfl_xor(sq, 1);
            s += __shfl_xor(s, 2); sq += __shfl_xor(sq, 2);
            s += __shfl_xor(s, 4); sq += __shfl_xor(sq, 4);
            s += __shfl_xor(s, 8); sq += __shfl_xor(sq, 8);
            if (l16 == 0) {
                ps[row * 4 + wv] = s;
                pq[row * 4 + wv] = sq;
            }
        }
    }
    __syncthreads();
    if (tid < 64) {
        float s  = ps[tid * 4] + ps[tid * 4 + 1] + ps[tid * 4 + 2] + ps[tid * 4 + 3];
        float sq = pq[tid * 4] + pq[tid * 4 + 1] + pq[tid * 4 + 2] + pq[tid * 4 + 3];
        float mu = s * (1.f / D);
        mu_s[tid] = mu;
        rs_s[tid] = rsqrtf(sq * (1.f / D) - mu * mu + LN_EPS);
    }
    __syncthreads();

    // ---- pass 2: normalize + ReLU + store ----
    float gc[4], bc[4];
#pragma unroll
    for (int nf = 0; nf < 4; ++nf) {
        gc[nf] = gln[col[nf]];
        bc[nf] = bln[col[nf]];
    }
#pragma unroll
    for (int mf = 0; mf < 4; ++mf) {
#pragma unroll
        for (int rr = 0; rr < 4; ++rr) {
            int row = mf * 16 + quad * 4 + rr;
            int n = nb + row;
            if (n >= N) continue;
            float mu = mu_s[row], rs = rs_s[row];
            float* op = hout + (size_t)n * D;
#pragma unroll
            for (int nf = 0; nf < 4; ++nf) {
                float o = fmaxf((acc[mf][nf][rr] - mu) * rs * gc[nf] + bc[nf], 0.f);
                op[col[nf]] = o;
                if (houtb) houtb[(size_t)n * D + col[nf]] = f2bf(o);
            }
        }
    }
}

extern "C" void kernel_launch(void* const* d_in, const int* in_sizes, int n_in,
                              void* d_out, int out_size, void* d_ws, size_t ws_size,
                              hipStream_t stream) {
    const float* x      = (const float*)d_in[0];
    const int*   ei     = (const int*)d_in[1];
    const int*   et     = (const int*)d_in[2];
    const float* ea     = (const float*)d_in[3];
    const float* basis1 = (const float*)d_in[4];
    const float* att1   = (const float*)d_in[5];
    const float* root1  = (const float*)d_in[6];
    const float* bias1  = (const float*)d_in[7];
    const float* g1     = (const float*)d_in[8];
    const float* b1     = (const float*)d_in[9];
    const float* basis2 = (const float*)d_in[10];
    const float* att2   = (const float*)d_in[11];
    const float* root2  = (const float*)d_in[12];
    const float* bias2  = (const float*)d_in[13];
    const float* g2     = (const float*)d_in[14];
    const float* b2     = (const float*)d_in[15];
    float* out = (float*)d_out;

    int N = in_sizes[0] / D;
    int E = in_sizes[2];
    int nch = (N + 255) / 256;
    int Mp = ((N + 63) / 64) * 64;
    int T = Mp / 64;
    int n4 = N * D / 4;

    char* p = (char*)d_ws;
    size_t used = 0;
    auto alloc = [&](size_t bytes) {
        char* q = p;
        size_t a = (bytes + 255) & ~(size_t)255;
        p += a; used += a;
        return q;
    };
    float*          h1     = (float*)alloc((size_t)N * D * 4);
    unsigned short* xb     = (unsigned short*)alloc((size_t)N * D * 2);
    unsigned short* h1b    = (unsigned short*)alloc((size_t)N * D * 2);
    unsigned short* Wt1    = (unsigned short*)alloc((size_t)K9 * D * 2);
    unsigned short* Wt2    = (unsigned short*)alloc((size_t)K9 * D * 2);
    int*            deg    = (int*)alloc((size_t)N * 4);
    int*            rowptr = (int*)alloc((size_t)(N + 1) * 4);
    int*            cursor = (int*)alloc((size_t)N * 4);
    float*          cnt    = (float*)alloc((size_t)N * 4);
    int2*           ep     = (int2*)alloc((size_t)E * 8);
    int*            csum   = (int*)alloc((size_t)nch * 4);
    size_t remain = (ws_size > used + 256) ? (ws_size - used - 256) : 0;
    size_t tile_bytes = (size_t)64 * K9 * 2;
    int ct = (int)(remain / tile_bytes);
    if (ct < 1) ct = 1;
    if (ct > T) ct = T;
    unsigned short* G = (unsigned short*)alloc((size_t)ct * tile_bytes);

    hipMemsetAsync(deg, 0, (size_t)N * 4, stream);
    int gE = (E + 255) / 256;
    int gPre = ((n4 > E ? n4 : E) + 255) / 256;
    k_pre<<<gPre, 256, 0, stream>>>(x, xb, n4, ei, deg, E);
    k_scan1<<<nch, 256, 0, stream>>>(deg, csum, N);
    k_scan2<<<1, 256, 0, stream>>>(csum, nch, rowptr, N);
    k_scan3<<<nch, 256, 0, stream>>>(deg, csum, rowptr, cursor, cnt, N);
    k_scatter<<<gE, 256, 0, stream>>>(ei, et, ea, cursor, ep, E);
    k_prep_w<<<dim3(K9 / 64, D / 64, 2), 256, 0, stream>>>(basis1, root1, Wt1,
                                                           basis2, root2, Wt2);

    const float* attp[2] = {att1, att2};
    const float* bi[2]   = {bias1, bias2};
    const float* lg[2]   = {g1, g2};
    const float* lb[2]   = {b1, b2};
    const unsigned short* gin[2] = {xb, h1b};
    const unsigned short* wt[2]  = {Wt1, Wt2};
    const float* hres[2] = {x, h1};
    float*          hof[2] = {h1, out};
    unsigned short* hob[2] = {h1b, nullptr};

    for (int L = 0; L < 2; ++L) {
        for (int c0 = 0; c0 < T; c0 += ct) {
            int tiles = (T - c0 < ct) ? (T - c0) : ct;
            int rows = tiles * 64;
            int n0 = c0 * 64;
            k_gather<<<rows / 4, 256, 0, stream>>>(gin[L], attp[L], rowptr, ep,
                                                   cnt, G, n0, rows, N);
            k_gemm<<<tiles, 256, 0, stream>>>(G, wt[L], hres[L], cnt, bi[L], lg[L], lb[L],
                                              hof[L], hob[L], n0, N);
        }
    }
}

// Round 8
// 988.630 us; speedup vs baseline: 1.5991x; 1.5991x over previous
//
#include <hip/hip_runtime.h>
#include <stdint.h>

#define D 256
#define RREL 16
#define BB 8
#define K9 2304          // (BB+1)*D
#define KIT (K9 / 64)    // 36 k-iterations
#define LN_EPS 1e-5f

typedef __attribute__((ext_vector_type(8))) short frag8;
typedef __attribute__((ext_vector_type(4))) float floatx4;

__device__ __forceinline__ unsigned short f2bf(float f) {
    union { float f; uint32_t u; } v; v.f = f;
    uint32_t r = (v.u + 0x7FFFu + ((v.u >> 16) & 1u)) >> 16;
    return (unsigned short)r;
}
__device__ __forceinline__ float bf2f(unsigned short u) {
    union { uint32_t u; float f; } v; v.u = (uint32_t)u << 16;
    return v.f;
}

__device__ __forceinline__ void gl2lds16(const unsigned short* g, char* l) {
    __builtin_amdgcn_global_load_lds((const __attribute__((address_space(1))) void*)g,
                                     (__attribute__((address_space(3))) void*)l, 16, 0, 0);
}

// ---------- fused: fp32->bf16 convert + degree histogram (validated in R5) ----------
__global__ __launch_bounds__(256) void k_pre(const float* __restrict__ x,
                                             unsigned short* __restrict__ xb, int n4,
                                             const int* __restrict__ ei,
                                             int* __restrict__ deg, int E) {
    int i = blockIdx.x * 256 + threadIdx.x;
    if (i < n4) {
        float4 v = ((const float4*)x)[i];
        ((ushort4*)xb)[i] = make_ushort4(f2bf(v.x), f2bf(v.y), f2bf(v.z), f2bf(v.w));
    }
    if (i < E) atomicAdd(&deg[ei[E + i]], 1);
}

// ---------- CSR scans ----------
__global__ __launch_bounds__(256) void k_scan1(const int* __restrict__ deg,
                                               int* __restrict__ csum, int N) {
    __shared__ int sh[256];
    int n = blockIdx.x * 256 + threadIdx.x;
    sh[threadIdx.x] = (n < N) ? deg[n] : 0;
    __syncthreads();
    for (int off = 128; off > 0; off >>= 1) {
        if (threadIdx.x < off) sh[threadIdx.x] += sh[threadIdx.x + off];
        __syncthreads();
    }
    if (threadIdx.x == 0) csum[blockIdx.x] = sh[0];
}

// parallel exclusive scan of chunk sums (nch <= 256 fast path; validated in R5)
__global__ __launch_bounds__(256) void k_scan2(int* __restrict__ csum, int nch,
                                               int* __restrict__ rowptr, int N) {
    int tid = threadIdx.x;
    if (nch <= 256) {
        __shared__ int sh[256];
        int v = (tid < nch) ? csum[tid] : 0;
        sh[tid] = v;
        __syncthreads();
        for (int off = 1; off < 256; off <<= 1) {
            int t = (tid >= off) ? sh[tid - off] : 0;
            __syncthreads();
            sh[tid] += t;
            __syncthreads();
        }
        if (tid < nch) csum[tid] = sh[tid] - v;
        if (tid == 255) rowptr[N] = sh[255];
    } else if (tid == 0) {
        int s = 0;
        for (int i = 0; i < nch; ++i) { int c = csum[i]; csum[i] = s; s += c; }
        rowptr[N] = s;
    }
}

__global__ __launch_bounds__(256) void k_scan3(const int* __restrict__ deg,
                                               const int* __restrict__ csum,
                                               int* __restrict__ rowptr,
                                               int* __restrict__ cursor,
                                               float* __restrict__ cnt, int N) {
    __shared__ int sh[256];
    int tid = threadIdx.x;
    int n = blockIdx.x * 256 + tid;
    int v = (n < N) ? deg[n] : 0;
    sh[tid] = v;
    __syncthreads();
    for (int off = 1; off < 256; off <<= 1) {
        int t = (tid >= off) ? sh[tid - off] : 0;
        __syncthreads();
        sh[tid] += t;
        __syncthreads();
    }
    int excl = sh[tid] - v + csum[blockIdx.x];
    if (n < N) {
        rowptr[n] = excl;
        cursor[n] = excl;
        cnt[n] = (float)(v + 1);
    }
}

__global__ void k_scatter(const int* __restrict__ ei, const int* __restrict__ et,
                          const float* __restrict__ ea, int* __restrict__ cursor,
                          int2* __restrict__ ep, int E) {
    int e = blockIdx.x * 256 + threadIdx.x;
    if (e >= E) return;
    int dst = ei[E + e];
    int p = atomicAdd(&cursor[dst], 1);
    ep[p] = make_int2(ei[e] | (et[e] << 24), __float_as_int(ea[e]));
}

// ---------- weight prep, both layers in one dispatch (validated in R5) ----------
__global__ __launch_bounds__(256) void k_prep_w(const float* __restrict__ basis1,
                                                const float* __restrict__ root1,
                                                unsigned short* __restrict__ Wt1,
                                                const float* __restrict__ basis2,
                                                const float* __restrict__ root2,
                                                unsigned short* __restrict__ Wt2) {
    __shared__ float tile[64][65];
    const float* basis = blockIdx.z ? basis2 : basis1;
    const float* root  = blockIdx.z ? root2 : root1;
    unsigned short* Wt = blockIdx.z ? Wt2 : Wt1;
    int k0 = blockIdx.x * 64, o0 = blockIdx.y * 64;
    const float* src = (k0 < BB * D) ? (basis + (size_t)k0 * D)
                                     : (root + (size_t)(k0 - BB * D) * D);
    int tid = threadIdx.x;
#pragma unroll
    for (int t = 0; t < 16; ++t) {
        int idx = t * 256 + tid;
        int kk = idx >> 6, oo = idx & 63;
        tile[kk][oo] = src[(size_t)kk * D + o0 + oo];
    }
    __syncthreads();
#pragma unroll
    for (int t = 0; t < 16; ++t) {
        int idx = t * 256 + tid;
        int oo = idx >> 6, kk = idx & 63;
        Wt[(size_t)(o0 + oo) * K9 + k0 + kk] = f2bf(tile[kk][oo]);
    }
}

// ---------- gather: one wave per node, bf16 in/out, 4-deep edge unroll ----------
__global__ __launch_bounds__(256) void k_gather(
    const unsigned short* __restrict__ xb, const float* __restrict__ att,
    const int* __restrict__ rowptr, const int2* __restrict__ ep,
    const float* __restrict__ cnt, unsigned short* __restrict__ G,
    int n0, int rows, int N) {
    __shared__ float att_s[RREL * BB];
    int tid = threadIdx.x;
    if (tid < RREL * BB) att_s[tid] = att[tid];
    __syncthreads();
    int wv = tid >> 6, lane = tid & 63;
    int rloc = blockIdx.x * 4 + wv;
    if (rloc >= rows) return;
    int n = n0 + rloc;
    unsigned short* gout = G + (size_t)rloc * K9 + lane * 4;
    if (n >= N) {
        ushort4 z = make_ushort4(0, 0, 0, 0);
#pragma unroll
        for (int b = 0; b <= BB; ++b) *(ushort4*)(gout + b * D) = z;
        return;
    }
    ushort4 xu = *(const ushort4*)&xb[(size_t)n * D + lane * 4];
    float xv[4] = {bf2f(xu.x), bf2f(xu.y), bf2f(xu.z), bf2f(xu.w)};
    float g[BB][4];
#pragma unroll
    for (int b = 0; b < BB; ++b) {
        float a = att_s[(RREL - 1) * BB + b];
#pragma unroll
        for (int j = 0; j < 4; ++j) g[b][j] = a * xv[j];
    }
    int e0 = rowptr[n], e1 = rowptr[n + 1];
    int e = e0;
    for (; e + 4 <= e1; e += 4) {           // 4 outstanding row loads
        int2 p0 = ep[e], p1 = ep[e + 1], p2 = ep[e + 2], p3 = ep[e + 3];
        ushort4 u0 = *(const ushort4*)&xb[(size_t)(p0.x & 0xFFFFFF) * D + lane * 4];
        ushort4 u1 = *(const ushort4*)&xb[(size_t)(p1.x & 0xFFFFFF) * D + lane * 4];
        ushort4 u2 = *(const ushort4*)&xb[(size_t)(p2.x & 0xFFFFFF) * D + lane * 4];
        ushort4 u3 = *(const ushort4*)&xb[(size_t)(p3.x & 0xFFFFFF) * D + lane * 4];
        float w0 = __int_as_float(p0.y), w1 = __int_as_float(p1.y);
        float w2 = __int_as_float(p2.y), w3 = __int_as_float(p3.y);
        int r0 = (unsigned)p0.x >> 24, r1 = (unsigned)p1.x >> 24;
        int r2 = (unsigned)p2.x >> 24, r3 = (unsigned)p3.x >> 24;
        float a0[4] = {bf2f(u0.x), bf2f(u0.y), bf2f(u0.z), bf2f(u0.w)};
        float a1[4] = {bf2f(u1.x), bf2f(u1.y), bf2f(u1.z), bf2f(u1.w)};
        float a2[4] = {bf2f(u2.x), bf2f(u2.y), bf2f(u2.z), bf2f(u2.w)};
        float a3[4] = {bf2f(u3.x), bf2f(u3.y), bf2f(u3.z), bf2f(u3.w)};
#pragma unroll
        for (int b = 0; b < BB; ++b) {
            float c0 = w0 * att_s[r0 * BB + b];
            float c1 = w1 * att_s[r1 * BB + b];
            float c2 = w2 * att_s[r2 * BB + b];
            float c3 = w3 * att_s[r3 * BB + b];
#pragma unroll
            for (int j = 0; j < 4; ++j)
                g[b][j] += c0 * a0[j] + c1 * a1[j] + c2 * a2[j] + c3 * a3[j];
        }
    }
    for (; e < e1; ++e) {
        int2 pa = ep[e];
        ushort4 ua = *(const ushort4*)&xb[(size_t)(pa.x & 0xFFFFFF) * D + lane * 4];
        float wa = __int_as_float(pa.y);
        int ra = (unsigned)pa.x >> 24;
        float xa[4] = {bf2f(ua.x), bf2f(ua.y), bf2f(ua.z), bf2f(ua.w)};
#pragma unroll
        for (int b = 0; b < BB; ++b) {
            float ca = wa * att_s[ra * BB + b];
#pragma unroll
            for (int j = 0; j < 4; ++j) g[b][j] += ca * xa[j];
        }
    }
#pragma unroll
    for (int b = 0; b < BB; ++b) {
        ushort4 o = make_ushort4(f2bf(g[b][0]), f2bf(g[b][1]), f2bf(g[b][2]), f2bf(g[b][3]));
        *(ushort4*)(gout + b * D) = o;
    }
    float cn = cnt[n];
    ushort4 o = make_ushort4(f2bf(cn * xv[0]), f2bf(cn * xv[1]),
                             f2bf(cn * xv[2]), f2bf(cn * xv[3]));
    *(ushort4*)(gout + BB * D) = o;
}

// ---------- fused GEMM (64x256, K=2304, bf16 MFMA) + mean + residual + LN + ReLU ----------
// A: direct global->VGPR fragments (G rows are k-contiguous), prefetched 1 iter ahead.
// B: LDS double-buffer (2x32KB); tile it+1 staged via global_load_lds right after the
// top-of-iter barrier -> compiler's vmcnt(0)-before-barrier only waits on loads issued
// a full MFMA phase earlier. launch_bounds(256,2): 256-VGPR budget; audit ~196, no spill.
__global__ __launch_bounds__(256, 2) void k_gemm(
    const unsigned short* __restrict__ G, const unsigned short* __restrict__ Wt,
    const float* __restrict__ hin, const float* __restrict__ cnt,
    const float* __restrict__ bias, const float* __restrict__ gln,
    const float* __restrict__ bln, float* __restrict__ hout,
    unsigned short* __restrict__ houtb, int n0, int N) {
    __shared__ __align__(16) char smem[65536];   // B dbuf: [2][256 cols][128 B]
    float* ps   = (float*)smem;          // epilogue aliases (B buffers dead then)
    float* pq   = ps + 256;
    float* mu_s = ps + 512;
    float* rs_s = ps + 576;

    int tid = threadIdx.x;
    int wv = tid >> 6, lane = tid & 63;
    int quad = lane >> 4, l16 = lane & 15;
    int grow = blockIdx.x * 64;
    int nb = n0 + grow;

    const unsigned short* gB[8];
    char* lB[8];
#pragma unroll
    for (int t = 0; t < 8; ++t) {
        int s = (wv * 8 + t) * 64 + lane;
        int col = s >> 3, gs = s & 7;
        gB[t] = Wt + (size_t)col * K9 + ((gs ^ (col & 7)) << 3);
        lB[t] = smem + ((wv * 8 + t) << 10);
    }
    const unsigned short* aptr[4];
#pragma unroll
    for (int mf = 0; mf < 4; ++mf)
        aptr[mf] = G + (size_t)(grow + mf * 16 + l16) * K9 + quad * 8;

    floatx4 acc[4][4];
#pragma unroll
    for (int mf = 0; mf < 4; ++mf)
#pragma unroll
        for (int nf = 0; nf < 4; ++nf) acc[mf][nf] = (floatx4){0.f, 0.f, 0.f, 0.f};

    frag8 aCur[8], aNxt[8];
#pragma unroll
    for (int t = 0; t < 8; ++t) gl2lds16(gB[t], lB[t]);
#pragma unroll
    for (int kc = 0; kc < 2; ++kc)
#pragma unroll
        for (int mf = 0; mf < 4; ++mf)
            aCur[kc * 4 + mf] = *(const frag8*)(aptr[mf] + kc * 32);

    for (int it = 0; it < KIT; ++it) {
        int sel = it & 1;
        __syncthreads();   // frees buf[sel^1]; drains B(it)/A(it) issued 1 iter ago
        if (it + 1 < KIT) {
            int koff = (it + 1) * 64;
            int obuf = (sel ^ 1) << 15;
#pragma unroll
            for (int t = 0; t < 8; ++t) gl2lds16(gB[t] + koff, lB[t] + obuf);
#pragma unroll
            for (int kc = 0; kc < 2; ++kc)
#pragma unroll
                for (int mf = 0; mf < 4; ++mf)
                    aNxt[kc * 4 + mf] = *(const frag8*)(aptr[mf] + koff + kc * 32);
        }
        char* Bbase = smem + (sel << 15);
#pragma unroll
        for (int kc = 0; kc < 2; ++kc) {
            int g = kc * 4 + quad;
            frag8 b[4];
#pragma unroll
            for (int nf = 0; nf < 4; ++nf) {
                int brow = wv * 64 + nf * 16 + l16;
                b[nf] = *(const frag8*)(Bbase + brow * 128 + ((g ^ (brow & 7)) << 4));
            }
#pragma unroll
            for (int mf = 0; mf < 4; ++mf)
#pragma unroll
                for (int nf = 0; nf < 4; ++nf)
                    acc[mf][nf] = __builtin_amdgcn_mfma_f32_16x16x32_bf16(
                        aCur[kc * 4 + mf], b[nf], acc[mf][nf], 0, 0, 0);
        }
#pragma unroll
        for (int t = 0; t < 8; ++t) aCur[t] = aNxt[t];
    }
    __syncthreads();

    // ---- pass 1: val = acc/cnt + residual + bias; LN partials ----
    int col[4]; float bic[4];
#pragma unroll
    for (int nf = 0; nf < 4; ++nf) {
        col[nf] = wv * 64 + nf * 16 + l16;
        bic[nf] = bias[col[nf]];
    }
#pragma unroll
    for (int mf = 0; mf < 4; ++mf) {
#pragma unroll
        for (int rr = 0; rr < 4; ++rr) {
            int row = mf * 16 + quad * 4 + rr;
            int n = nb + row;
            float s = 0.f, sq = 0.f;
            if (n < N) {
                float inv = 1.0f / cnt[n];
                const float* hp = hin + (size_t)n * D;
#pragma unroll
                for (int nf = 0; nf < 4; ++nf) {
                    float v = acc[mf][nf][rr] * inv + hp[col[nf]] + bic[nf];
                    acc[mf][nf][rr] = v;
                    s += v; sq += v * v;
                }
            }
            s += __shfl_xor(s, 1); sq += __shfl_xor(sq, 1);
            s += __shfl_xor(s, 2); sq += __shfl_xor(sq, 2);
            s += __shfl_xor(s, 4); sq += __shfl_xor(sq, 4);
            s += __shfl_xor(s, 8); sq += __shfl_xor(sq, 8);
            if (l16 == 0) {
                ps[row * 4 + wv] = s;
                pq[row * 4 + wv] = sq;
            }
        }
    }
    __syncthreads();
    if (tid < 64) {
        float s  = ps[tid * 4] + ps[tid * 4 + 1] + ps[tid * 4 + 2] + ps[tid * 4 + 3];
        float sq = pq[tid * 4] + pq[tid * 4 + 1] + pq[tid * 4 + 2] + pq[tid * 4 + 3];
        float mu = s * (1.f / D);
        mu_s[tid] = mu;
        rs_s[tid] = rsqrtf(sq * (1.f / D) - mu * mu + LN_EPS);
    }
    __syncthreads();

    // ---- pass 2: normalize + ReLU + store ----
    float gc[4], bc[4];
#pragma unroll
    for (int nf = 0; nf < 4; ++nf) {
        gc[nf] = gln[col[nf]];
        bc[nf] = bln[col[nf]];
    }
#pragma unroll
    for (int mf = 0; mf < 4; ++mf) {
#pragma unroll
        for (int rr = 0; rr < 4; ++rr) {
            int row = mf * 16 + quad * 4 + rr;
            int n = nb + row;
            if (n >= N) continue;
            float mu = mu_s[row], rs = rs_s[row];
            float* op = hout + (size_t)n * D;
#pragma unroll
            for (int nf = 0; nf < 4; ++nf) {
                float o = fmaxf((acc[mf][nf][rr] - mu) * rs * gc[nf] + bc[nf], 0.f);
                op[col[nf]] = o;
                if (houtb) houtb[(size_t)n * D + col[nf]] = f2bf(o);
            }
        }
    }
}

extern "C" void kernel_launch(void* const* d_in, const int* in_sizes, int n_in,
                              void* d_out, int out_size, void* d_ws, size_t ws_size,
                              hipStream_t stream) {
    const float* x      = (const float*)d_in[0];
    const int*   ei     = (const int*)d_in[1];
    const int*   et     = (const int*)d_in[2];
    const float* ea     = (const float*)d_in[3];
    const float* basis1 = (const float*)d_in[4];
    const float* att1   = (const float*)d_in[5];
    const float* root1  = (const float*)d_in[6];
    const float* bias1  = (const float*)d_in[7];
    const float* g1     = (const float*)d_in[8];
    const float* b1     = (const float*)d_in[9];
    const float* basis2 = (const float*)d_in[10];
    const float* att2   = (const float*)d_in[11];
    const float* root2  = (const float*)d_in[12];
    const float* bias2  = (const float*)d_in[13];
    const float* g2     = (const float*)d_in[14];
    const float* b2     = (const float*)d_in[15];
    float* out = (float*)d_out;

    int N = in_sizes[0] / D;
    int E = in_sizes[2];
    int nch = (N + 255) / 256;
    int Mp = ((N + 63) / 64) * 64;
    int T = Mp / 64;
    int n4 = N * D / 4;

    char* p = (char*)d_ws;
    size_t used = 0;
    auto alloc = [&](size_t bytes) {
        char* q = p;
        size_t a = (bytes + 255) & ~(size_t)255;
        p += a; used += a;
        return q;
    };
    float*          h1     = (float*)alloc((size_t)N * D * 4);
    unsigned short* xb     = (unsigned short*)alloc((size_t)N * D * 2);
    unsigned short* h1b    = (unsigned short*)alloc((size_t)N * D * 2);
    unsigned short* Wt1    = (unsigned short*)alloc((size_t)K9 * D * 2);
    unsigned short* Wt2    = (unsigned short*)alloc((size_t)K9 * D * 2);
    int*            deg    = (int*)alloc((size_t)N * 4);
    int*            rowptr = (int*)alloc((size_t)(N + 1) * 4);
    int*            cursor = (int*)alloc((size_t)N * 4);
    float*          cnt    = (float*)alloc((size_t)N * 4);
    int2*           ep     = (int2*)alloc((size_t)E * 8);
    int*            csum   = (int*)alloc((size_t)nch * 4);
    size_t remain = (ws_size > used + 256) ? (ws_size - used - 256) : 0;
    size_t tile_bytes = (size_t)64 * K9 * 2;
    int ct = (int)(remain / tile_bytes);
    if (ct < 1) ct = 1;
    if (ct > T) ct = T;
    unsigned short* G = (unsigned short*)alloc((size_t)ct * tile_bytes);

    hipMemsetAsync(deg, 0, (size_t)N * 4, stream);
    int gE = (E + 255) / 256;
    int gPre = ((n4 > E ? n4 : E) + 255) / 256;
    k_pre<<<gPre, 256, 0, stream>>>(x, xb, n4, ei, deg, E);
    k_scan1<<<nch, 256, 0, stream>>>(deg, csum, N);
    k_scan2<<<1, 256, 0, stream>>>(csum, nch, rowptr, N);
    k_scan3<<<nch, 256, 0, stream>>>(deg, csum, rowptr, cursor, cnt, N);
    k_scatter<<<gE, 256, 0, stream>>>(ei, et, ea, cursor, ep, E);
    k_prep_w<<<dim3(K9 / 64, D / 64, 2), 256, 0, stream>>>(basis1, root1, Wt1,
                                                           basis2, root2, Wt2);

    const float* attp[2] = {att1, att2};
    const float* bi[2]   = {bias1, bias2};
    const float* lg[2]   = {g1, g2};
    const float* lb[2]   = {b1, b2};
    const unsigned short* gin[2] = {xb, h1b};
    const unsigned short* wt[2]  = {Wt1, Wt2};
    const float* hres[2] = {x, h1};
    float*          hof[2] = {h1, out};
    unsigned short* hob[2] = {h1b, nullptr};

    for (int L = 0; L < 2; ++L) {
        for (int c0 = 0; c0 < T; c0 += ct) {
            int tiles = (T - c0 < ct) ? (T - c0) : ct;
            int rows = tiles * 64;
            int n0 = c0 * 64;
            k_gather<<<rows / 4, 256, 0, stream>>>(gin[L], attp[L], rowptr, ep,
                                                   cnt, G, n0, rows, N);
            k_gemm<<<tiles, 256, 0, stream>>>(G, wt[L], hres[L], cnt, bi[L], lg[L], lb[L],
                                              hof[L], hob[L], n0, N);
        }
    }
}